// Round 7
// baseline (150.735 us; speedup 1.0000x reference)
//
#include <hip/hip_runtime.h>

typedef unsigned char u8;
typedef unsigned short u16;
typedef float f32x4 __attribute__((ext_vector_type(4)));
typedef long l2 __attribute__((ext_vector_type(2)));
typedef int i32x4 __attribute__((ext_vector_type(4)));
typedef int i32x8 __attribute__((ext_vector_type(8)));

#define NROWS 16384
#define DIM 128

// exp(-2*sim) = exp2(sim * -2*log2(e)); scale folded into normalized B rows.
#define NEG2LOG2E -2.8853900817779268f
#define SCALE ((float)(1.0 / (16384.0 * 16383.0)))

// E8M0 scale byte 127 = 2^0 = 1.0, replicated.
#define SCALE1 0x7F7F7F7F

// One wave per row: L2-normalize rows of a and b, emit fp8 e4m3 (OCP).
// B rows pre-scaled by -2*log2(e) so GEMM output feeds exp2 directly.
__global__ __launch_bounds__(256) void norm_kernel(
    const float* __restrict__ a, const float* __restrict__ b,
    u8* __restrict__ aO, u8* __restrict__ bO)
{
    int tid  = threadIdx.x;
    int lane = tid & 63;
    int w    = tid >> 6;
    long row = (long)blockIdx.x * 4 + w;

    const float2 va = ((const float2*)(a + row * DIM))[lane];
    float sa = va.x * va.x + va.y * va.y;
    #pragma unroll
    for (int off = 32; off; off >>= 1) sa += __shfl_xor(sa, off, 64);
    float inva = 1.0f / fmaxf(sqrtf(sa), 1e-12f);
    unsigned int pa = (unsigned int)__builtin_amdgcn_cvt_pk_fp8_f32(
        va.x * inva, va.y * inva, 0, false);
    ((u16*)(aO + row * DIM))[lane] = (u16)(pa & 0xffffu);

    const float2 vb = ((const float2*)(b + row * DIM))[lane];
    float sb = vb.x * vb.x + vb.y * vb.y;
    #pragma unroll
    for (int off = 32; off; off >>= 1) sb += __shfl_xor(sb, off, 64);
    float invb = NEG2LOG2E / fmaxf(sqrtf(sb), 1e-12f);
    unsigned int pb = (unsigned int)__builtin_amdgcn_cvt_pk_fp8_f32(
        vb.x * invb, vb.y * invb, 0, false);
    ((u16*)(bO + row * DIM))[lane] = (u16)(pb & 0xffffu);
}

// Group row indices by label (labels in [0,100)). offs[101] prefix table,
// idx[16384] row indices bucketed by label. One block.
__global__ __launch_bounds__(256) void bucket_kernel(
    const int* __restrict__ labels, int* __restrict__ offs, int* __restrict__ idx)
{
    __shared__ int cnt[100];
    __shared__ int cur[100];
    int tid = threadIdx.x;
    if (tid < 100) cnt[tid] = 0;
    __syncthreads();
    for (int i = tid; i < NROWS; i += 256)
        atomicAdd(&cnt[labels[i]], 1);
    __syncthreads();
    if (tid == 0) {
        int run = 0;
        for (int l = 0; l < 100; l++) { cur[l] = run; offs[l] = run; run += cnt[l]; }
        offs[100] = run;
    }
    __syncthreads();
    for (int i = tid; i < NROWS; i += 256) {
        int p = atomicAdd(&cur[labels[i]], 1);
        idx[p] = i;
    }
}

// Each block: 128 rows x 512 cols = 4 column-tiles of 128x128. MASKLESS:
// sums exp over ALL pairs; same-label pairs subtracted by corr_kernel with
// bit-identical MFMA+exp math (exact cancellation).
// A tile (16 KB) staged once, A-operands register-resident (32 VGPRs).
// B double-buffered (2 x 16 KB): [issue DMA B_{t+1}] -> compute t -> barrier.
// MX-scaled fp8 MFMA 16x16x128 (scale=1.0): one instr per (mi,ni) covers
// K=128 at 2x rate. Operand = 32 B/lane = the same two swizzled b128
// granules as before (low half ^0, high half ^16).
__global__ __launch_bounds__(256, 3) void gemm_kernel(
    const u8* __restrict__ A, const u8* __restrict__ B,
    float* __restrict__ partials)
{
    __shared__ u8 sA[16384];
    __shared__ u8 sB[2][16384];

    int tid  = threadIdx.x;
    int lane = tid & 63;
    int w    = tid >> 6;
    int wr   = w >> 1;
    int wc   = w & 1;
    int mrow = lane & 15;
    int q    = lane >> 4;

    int rowBase = blockIdx.y * 128;      // grid (32,128): x = column group
    int colBase = blockIdx.x * 512;

    // Staging pattern: LDS granule g of row m holds global granule g^(m&7).
    int m0 = tid >> 3;
    int p0 = tid & 7;
    int srcOff = m0 * 128 + ((p0 ^ (m0 & 7)) << 4);
    int ldsOff = (tid - lane) * 16;      // wave-uniform base

    const u8* gA = A + (size_t)rowBase * DIM + srcOff;
    const u8* gB = B + (size_t)colBase * DIM + srcOff;

    {
        const u8* gpA = gA;
        const u8* gpB = gB;
        u8* lpA = &sA[ldsOff];
        u8* lpB = &sB[0][ldsOff];
        #pragma unroll
        for (int it = 0; it < 4; it++) {
            __builtin_amdgcn_global_load_lds(
                (const __attribute__((address_space(1))) void*)gpA,
                (__attribute__((address_space(3))) void*)lpA, 16, 0, 0);
            __builtin_amdgcn_global_load_lds(
                (const __attribute__((address_space(1))) void*)gpB,
                (__attribute__((address_space(3))) void*)lpB, 16, 0, 0);
            gpA += 4096; gpB += 4096; lpA += 4096; lpB += 4096;
        }
    }

    // Fragment LDS byte offsets: low granule (2q)^(row&7); high = ^16.
    int aOff[4], bOff[4];
    #pragma unroll
    for (int mi = 0; mi < 4; mi++) {
        int m = wr * 64 + mi * 16 + mrow;
        aOff[mi] = m * 128 + (((q << 1) ^ (m & 7)) << 4);
        int n = wc * 64 + mi * 16 + mrow;
        bOff[mi] = n * 128 + (((q << 1) ^ (n & 7)) << 4);
    }

    __syncthreads();   // A + B0 resident

    // A operands register-resident for all 4 tiles (32 VGPRs).
    i32x8 a8[4];
    #pragma unroll
    for (int mi = 0; mi < 4; mi++) {
        *((i32x4*)&a8[mi])     = *(const i32x4*)(sA + aOff[mi]);
        *((i32x4*)&a8[mi] + 1) = *(const i32x4*)(sA + (aOff[mi] ^ 16));
    }

    float s = 0.0f;

    #pragma unroll
    for (int jt = 0; jt < 4; jt++) {
        if (jt < 3) {
            const u8* gp = gB + (jt + 1) * (128 * DIM);
            u8* lp = &sB[(jt + 1) & 1][ldsOff];
            #pragma unroll
            for (int it = 0; it < 4; it++) {
                __builtin_amdgcn_global_load_lds(
                    (const __attribute__((address_space(1))) void*)gp,
                    (__attribute__((address_space(3))) void*)lp, 16, 0, 0);
                gp += 4096; lp += 4096;
            }
        }

        const u8* sb = sB[jt & 1];
        i32x8 b8[4];
        #pragma unroll
        for (int ni = 0; ni < 4; ni++) {
            *((i32x4*)&b8[ni])     = *(const i32x4*)(sb + bOff[ni]);
            *((i32x4*)&b8[ni] + 1) = *(const i32x4*)(sb + (bOff[ni] ^ 16));
        }

        f32x4 acc[4][4];
        #pragma unroll
        for (int mi = 0; mi < 4; mi++)
            #pragma unroll
            for (int ni = 0; ni < 4; ni++)
                acc[mi][ni] = (f32x4){0.f, 0.f, 0.f, 0.f};

        #pragma unroll
        for (int mi = 0; mi < 4; mi++)
            #pragma unroll
            for (int ni = 0; ni < 4; ni++)
                acc[mi][ni] = __builtin_amdgcn_mfma_scale_f32_16x16x128_f8f6f4(
                    a8[mi], b8[ni], acc[mi][ni], 0, 0, 0, SCALE1, 0, SCALE1);

        // Maskless epilogue: exp2 + add only.
        float s0 = 0.0f, s1 = 0.0f;
        #pragma unroll
        for (int mi = 0; mi < 4; mi++)
            #pragma unroll
            for (int ni = 0; ni < 4; ni++)
                #pragma unroll
                for (int r = 0; r < 4; r++) {
                    float e = __builtin_amdgcn_exp2f(acc[mi][ni][r]);
                    if (r & 1) s1 += e; else s0 += e;
                }
        s += s0 + s1;

        __syncthreads();
    }

    #pragma unroll
    for (int off = 32; off; off >>= 1) s += __shfl_xor(s, off, 64);

    float* red = (float*)sA;
    if (lane == 0) red[w] = s;
    __syncthreads();
    if (tid == 0) {
        float t = (red[0] + red[1]) + (red[2] + red[3]);
        partials[blockIdx.y * 32 + blockIdx.x] = t * SCALE;
    }
}

// One block per label: gather the label's rows of A and B into LDS, redo the
// identical MX-MFMA + exp2 on all same-label pairs, emit the sum to subtract.
#define KMAX 320
#define RSTR 144   // 9 x 16-B granules: row stride staggers banks
__global__ __launch_bounds__(512) void corr_kernel(
    const u8* __restrict__ A, const u8* __restrict__ B,
    const int* __restrict__ offs, const int* __restrict__ idx,
    float* __restrict__ corrP)
{
    __shared__ u8 sA[KMAX * RSTR];
    __shared__ u8 sB[KMAX * RSTR];
    __shared__ float red[8];

    int l   = blockIdx.x;
    int o0  = offs[l];
    int k   = offs[l + 1] - o0;
    if (k > KMAX) k = KMAX;              // statistically unreachable
    int tid = threadIdx.x;

    for (int t = tid; t < k * 8; t += 512) {
        int r = t >> 3, g = t & 7;
        int row = idx[o0 + r];
        *(float4*)(sA + r * RSTR + g * 16) = *(const float4*)(A + (size_t)row * DIM + g * 16);
        *(float4*)(sB + r * RSTR + g * 16) = *(const float4*)(B + (size_t)row * DIM + g * 16);
    }
    __syncthreads();

    int lane = tid & 63, w = tid >> 6;
    int mrow = lane & 15, q = lane >> 4;
    int nt = (k + 15) >> 4;
    float s = 0.0f;

    for (int tp = w; tp < nt * nt; tp += 8) {
        int ti = tp / nt, tj = tp - ti * nt;
        const u8* pa = sA + (ti * 16 + mrow) * RSTR + q * 32;
        const u8* pb = sB + (tj * 16 + mrow) * RSTR + q * 32;
        i32x8 aF, bF;
        *((i32x4*)&aF)     = *(const i32x4*)pa;
        *((i32x4*)&aF + 1) = *(const i32x4*)(pa + 16);
        *((i32x4*)&bF)     = *(const i32x4*)pb;
        *((i32x4*)&bF + 1) = *(const i32x4*)(pb + 16);
        f32x4 acc = (f32x4){0.f, 0.f, 0.f, 0.f};
        acc = __builtin_amdgcn_mfma_scale_f32_16x16x128_f8f6f4(
            aF, bF, acc, 0, 0, 0, SCALE1, 0, SCALE1);
        int i0 = ti * 16 + q * 4;
        int j  = tj * 16 + mrow;
        #pragma unroll
        for (int r = 0; r < 4; r++) {
            float e = __builtin_amdgcn_exp2f(acc[r]);
            s += ((i0 + r) < k && j < k) ? e : 0.0f;   // pad rows masked out
        }
    }

    #pragma unroll
    for (int off = 32; off; off >>= 1) s += __shfl_xor(s, off, 64);
    if (lane == 0) red[w] = s;
    __syncthreads();
    if (tid == 0) {
        float t = 0.f;
        #pragma unroll
        for (int i = 0; i < 8; i++) t += red[i];
        corrP[l] = t * SCALE;
    }
}

__global__ __launch_bounds__(256) void reduce_kernel(
    const float* __restrict__ gP, const float* __restrict__ cP,
    float* __restrict__ out)
{
    int tid = threadIdx.x;
    const float4* p4 = (const float4*)gP;
    float s = 0.0f;
    #pragma unroll 4
    for (int i = tid; i < 1024; i += 256) {
        float4 v = p4[i];
        s += (v.x + v.y) + (v.z + v.w);
    }
    if (tid < 100) s -= cP[tid];
    #pragma unroll
    for (int off = 32; off; off >>= 1) s += __shfl_xor(s, off, 64);
    __shared__ float red[4];
    if ((tid & 63) == 0) red[tid >> 6] = s;
    __syncthreads();
    if (tid == 0) out[0] = (red[0] + red[1]) + (red[2] + red[3]);
}

extern "C" void kernel_launch(void* const* d_in, const int* in_sizes, int n_in,
                              void* d_out, int out_size, void* d_ws, size_t ws_size,
                              hipStream_t stream) {
    const float* self_p = (const float*)d_in[0];
    const float* pos_p  = (const float*)d_in[1];
    const int*   labels = (const int*)d_in[2];
    float* out = (float*)d_out;

    u8* aB = (u8*)d_ws;                         // 2 MB fp8 normalized self
    u8* bB = aB + (size_t)NROWS * DIM;          // 2 MB fp8 normalized pos (pre-scaled)
    float* gemmP = (float*)(bB + (size_t)NROWS * DIM);     // 16 KB
    float* corrP = gemmP + 4096;                            // 512 B (100 used)
    int*   offs  = (int*)(corrP + 128);                     // 101 ints
    int*   idx   = offs + 128;                              // 64 KB

    bucket_kernel<<<1, 256, 0, stream>>>(labels, offs, idx);
    norm_kernel<<<NROWS / 4, 256, 0, stream>>>(self_p, pos_p, aB, bB);
    gemm_kernel<<<dim3(32, 128), 256, 0, stream>>>(aB, bB, gemmP);
    corr_kernel<<<100, 512, 0, stream>>>(aB, bB, offs, idx, corrP);
    reduce_kernel<<<1, 256, 0, stream>>>(gemmP, corrP, out);
}

// Round 8
// 145.318 us; speedup vs baseline: 1.0373x; 1.0373x over previous
//
#include <hip/hip_runtime.h>

typedef unsigned char u8;
typedef unsigned short u16;
typedef float f32x4 __attribute__((ext_vector_type(4)));
typedef int i32x4 __attribute__((ext_vector_type(4)));
typedef int i32x8 __attribute__((ext_vector_type(8)));

#define NROWS 16384
#define DIM 128

// exp(-2*sim) = exp2(sim * -2*log2(e)); scale folded into normalized B rows.
#define NEG2LOG2E -2.8853900817779268f
#define SCALE ((float)(1.0 / (16384.0 * 16383.0)))

// E8M0 scale byte 127 = 2^0 = 1.0, replicated.
#define SCALE1 0x7F7F7F7F

// One wave per row: L2-normalize rows of a and b, emit fp8 e4m3 (OCP).
// B rows pre-scaled by -2*log2(e) so GEMM output feeds exp2 directly.
__global__ __launch_bounds__(256) void norm_kernel(
    const float* __restrict__ a, const float* __restrict__ b,
    u8* __restrict__ aO, u8* __restrict__ bO)
{
    int tid  = threadIdx.x;
    int lane = tid & 63;
    int w    = tid >> 6;
    long row = (long)blockIdx.x * 4 + w;

    const float2 va = ((const float2*)(a + row * DIM))[lane];
    float sa = va.x * va.x + va.y * va.y;
    #pragma unroll
    for (int off = 32; off; off >>= 1) sa += __shfl_xor(sa, off, 64);
    float inva = 1.0f / fmaxf(sqrtf(sa), 1e-12f);
    unsigned int pa = (unsigned int)__builtin_amdgcn_cvt_pk_fp8_f32(
        va.x * inva, va.y * inva, 0, false);
    ((u16*)(aO + row * DIM))[lane] = (u16)(pa & 0xffffu);

    const float2 vb = ((const float2*)(b + row * DIM))[lane];
    float sb = vb.x * vb.x + vb.y * vb.y;
    #pragma unroll
    for (int off = 32; off; off >>= 1) sb += __shfl_xor(sb, off, 64);
    float invb = NEG2LOG2E / fmaxf(sqrtf(sb), 1e-12f);
    unsigned int pb = (unsigned int)__builtin_amdgcn_cvt_pk_fp8_f32(
        vb.x * invb, vb.y * invb, 0, false);
    ((u16*)(bO + row * DIM))[lane] = (u16)(pb & 0xffffu);
}

// Each block: 128 rows x 512 cols = 4 column-tiles of 128x128. MASKLESS:
// sums exp over ALL pairs; same-label pairs subtracted by corr_kernel with
// MFMA+exp math identical to fp8-GEMM rounding (exact cancellation).
// A tile (16 KB) staged once, A-operands register-resident (32 VGPRs).
// B double-buffered (2 x 16 KB): [issue DMA B_{t+1}] -> compute t -> barrier.
// MX-scaled fp8 MFMA 16x16x128 (scale=1.0): one instr per (mi,ni) covers
// K=128 at 2x rate. Operand = 32 B/lane = two swizzled b128 granules.
__global__ __launch_bounds__(256, 3) void gemm_kernel(
    const u8* __restrict__ A, const u8* __restrict__ B,
    float* __restrict__ partials)
{
    __shared__ u8 sA[16384];
    __shared__ u8 sB[2][16384];

    int tid  = threadIdx.x;
    int lane = tid & 63;
    int w    = tid >> 6;
    int wr   = w >> 1;
    int wc   = w & 1;
    int mrow = lane & 15;
    int q    = lane >> 4;

    int rowBase = blockIdx.y * 128;      // grid (32,128): x = column group
    int colBase = blockIdx.x * 512;

    // Staging pattern: LDS granule g of row m holds global granule g^(m&7).
    int m0 = tid >> 3;
    int p0 = tid & 7;
    int srcOff = m0 * 128 + ((p0 ^ (m0 & 7)) << 4);
    int ldsOff = (tid - lane) * 16;      // wave-uniform base

    const u8* gA = A + (size_t)rowBase * DIM + srcOff;
    const u8* gB = B + (size_t)colBase * DIM + srcOff;

    {
        const u8* gpA = gA;
        const u8* gpB = gB;
        u8* lpA = &sA[ldsOff];
        u8* lpB = &sB[0][ldsOff];
        #pragma unroll
        for (int it = 0; it < 4; it++) {
            __builtin_amdgcn_global_load_lds(
                (const __attribute__((address_space(1))) void*)gpA,
                (__attribute__((address_space(3))) void*)lpA, 16, 0, 0);
            __builtin_amdgcn_global_load_lds(
                (const __attribute__((address_space(1))) void*)gpB,
                (__attribute__((address_space(3))) void*)lpB, 16, 0, 0);
            gpA += 4096; gpB += 4096; lpA += 4096; lpB += 4096;
        }
    }

    // Fragment LDS byte offsets: low granule (2q)^(row&7); high = ^16.
    int aOff[4], bOff[4];
    #pragma unroll
    for (int mi = 0; mi < 4; mi++) {
        int m = wr * 64 + mi * 16 + mrow;
        aOff[mi] = m * 128 + (((q << 1) ^ (m & 7)) << 4);
        int n = wc * 64 + mi * 16 + mrow;
        bOff[mi] = n * 128 + (((q << 1) ^ (n & 7)) << 4);
    }

    __syncthreads();   // A + B0 resident

    // A operands register-resident for all 4 tiles (32 VGPRs).
    i32x8 a8[4];
    #pragma unroll
    for (int mi = 0; mi < 4; mi++) {
        *((i32x4*)&a8[mi])     = *(const i32x4*)(sA + aOff[mi]);
        *((i32x4*)&a8[mi] + 1) = *(const i32x4*)(sA + (aOff[mi] ^ 16));
    }

    float s = 0.0f;

    #pragma unroll
    for (int jt = 0; jt < 4; jt++) {
        if (jt < 3) {
            const u8* gp = gB + (jt + 1) * (128 * DIM);
            u8* lp = &sB[(jt + 1) & 1][ldsOff];
            #pragma unroll
            for (int it = 0; it < 4; it++) {
                __builtin_amdgcn_global_load_lds(
                    (const __attribute__((address_space(1))) void*)gp,
                    (__attribute__((address_space(3))) void*)lp, 16, 0, 0);
                gp += 4096; lp += 4096;
            }
        }

        const u8* sb = sB[jt & 1];
        i32x8 b8[4];
        #pragma unroll
        for (int ni = 0; ni < 4; ni++) {
            *((i32x4*)&b8[ni])     = *(const i32x4*)(sb + bOff[ni]);
            *((i32x4*)&b8[ni] + 1) = *(const i32x4*)(sb + (bOff[ni] ^ 16));
        }

        f32x4 acc[4][4];
        #pragma unroll
        for (int mi = 0; mi < 4; mi++)
            #pragma unroll
            for (int ni = 0; ni < 4; ni++)
                acc[mi][ni] = (f32x4){0.f, 0.f, 0.f, 0.f};

        #pragma unroll
        for (int mi = 0; mi < 4; mi++)
            #pragma unroll
            for (int ni = 0; ni < 4; ni++)
                acc[mi][ni] = __builtin_amdgcn_mfma_scale_f32_16x16x128_f8f6f4(
                    a8[mi], b8[ni], acc[mi][ni], 0, 0, 0, SCALE1, 0, SCALE1);

        // Maskless epilogue: exp2 + add only.
        float s0 = 0.0f, s1 = 0.0f;
        #pragma unroll
        for (int mi = 0; mi < 4; mi++)
            #pragma unroll
            for (int ni = 0; ni < 4; ni++)
                #pragma unroll
                for (int r = 0; r < 4; r++) {
                    float e = __builtin_amdgcn_exp2f(acc[mi][ni][r]);
                    if (r & 1) s1 += e; else s0 += e;
                }
        s += s0 + s1;

        __syncthreads();
    }

    #pragma unroll
    for (int off = 32; off; off >>= 1) s += __shfl_xor(s, off, 64);

    float* red = (float*)sA;
    if (lane == 0) red[w] = s;
    __syncthreads();
    if (tid == 0) {
        float t = (red[0] + red[1]) + (red[2] + red[3]);
        partials[blockIdx.y * 32 + blockIdx.x] = t * SCALE;
    }
}

// One block per label, no bucket pass, no row staging: self-scan the label
// array (L2 broadcast), compact this label's row indices into LDS, then
// each wave gathers 16x16 tile-pair fragments directly from global (L2-hot)
// and redoes the same MX-MFMA + exp2. Pad rows duplicate row 0, masked out
// by selection in the epilogue.
#define KMAX 320
__global__ __launch_bounds__(256) void corr_kernel(
    const u8* __restrict__ A, const u8* __restrict__ B,
    const int* __restrict__ labels, float* __restrict__ corrP)
{
    __shared__ int sIdx[KMAX];
    __shared__ int sCnt;
    __shared__ float red[4];

    int l   = blockIdx.x;
    int tid = threadIdx.x;
    if (tid == 0) sCnt = 0;
    __syncthreads();

    for (int i = tid; i < NROWS; i += 256)
        if (labels[i] == l) {
            int p = atomicAdd(&sCnt, 1);
            if (p < KMAX) sIdx[p] = i;
        }
    __syncthreads();

    int k = sCnt < KMAX ? sCnt : KMAX;
    int nt = (k + 15) >> 4;
    int ntk = nt << 4;
    for (int r = k + tid; r < ntk; r += 256) sIdx[r] = sIdx[0];  // pad
    __syncthreads();

    int lane = tid & 63, w = tid >> 6;
    int mrow = lane & 15, q = lane >> 4;
    float s = 0.0f;

    for (int tp = w; tp < nt * nt; tp += 4) {
        int ti = tp / nt, tj = tp - ti * nt;
        int ri = sIdx[ti * 16 + mrow];
        int rj = sIdx[tj * 16 + mrow];
        const u8* pa = A + (size_t)ri * DIM + q * 32;
        const u8* pb = B + (size_t)rj * DIM + q * 32;
        i32x8 aF, bF;
        *((i32x4*)&aF)     = *(const i32x4*)pa;
        *((i32x4*)&aF + 1) = *(const i32x4*)(pa + 16);
        *((i32x4*)&bF)     = *(const i32x4*)pb;
        *((i32x4*)&bF + 1) = *(const i32x4*)(pb + 16);
        f32x4 acc = (f32x4){0.f, 0.f, 0.f, 0.f};
        acc = __builtin_amdgcn_mfma_scale_f32_16x16x128_f8f6f4(
            aF, bF, acc, 0, 0, 0, SCALE1, 0, SCALE1);
        int i0 = ti * 16 + q * 4;
        int j  = tj * 16 + mrow;
        #pragma unroll
        for (int r = 0; r < 4; r++) {
            float e = __builtin_amdgcn_exp2f(acc[r]);
            s += ((i0 + r) < k && j < k) ? e : 0.0f;
        }
    }

    #pragma unroll
    for (int off = 32; off; off >>= 1) s += __shfl_xor(s, off, 64);
    if (lane == 0) red[w] = s;
    __syncthreads();
    if (tid == 0)
        corrP[l] = (red[0] + red[1] + red[2] + red[3]) * SCALE;
}

__global__ __launch_bounds__(256) void reduce_kernel(
    const float* __restrict__ gP, const float* __restrict__ cP,
    float* __restrict__ out)
{
    int tid = threadIdx.x;
    const float4* p4 = (const float4*)gP;
    float s = 0.0f;
    #pragma unroll 4
    for (int i = tid; i < 1024; i += 256) {
        float4 v = p4[i];
        s += (v.x + v.y) + (v.z + v.w);
    }
    if (tid < 100) s -= cP[tid];
    #pragma unroll
    for (int off = 32; off; off >>= 1) s += __shfl_xor(s, off, 64);
    __shared__ float red[4];
    if ((tid & 63) == 0) red[tid >> 6] = s;
    __syncthreads();
    if (tid == 0) out[0] = (red[0] + red[1]) + (red[2] + red[3]);
}

extern "C" void kernel_launch(void* const* d_in, const int* in_sizes, int n_in,
                              void* d_out, int out_size, void* d_ws, size_t ws_size,
                              hipStream_t stream) {
    const float* self_p = (const float*)d_in[0];
    const float* pos_p  = (const float*)d_in[1];
    const int*   labels = (const int*)d_in[2];
    float* out = (float*)d_out;

    u8* aB = (u8*)d_ws;                         // 2 MB fp8 normalized self
    u8* bB = aB + (size_t)NROWS * DIM;          // 2 MB fp8 normalized pos (pre-scaled)
    float* gemmP = (float*)(bB + (size_t)NROWS * DIM);     // 16 KB
    float* corrP = gemmP + 4096;                            // 512 B (100 used)

    norm_kernel<<<NROWS / 4, 256, 0, stream>>>(self_p, pos_p, aB, bB);
    gemm_kernel<<<dim3(32, 128), 256, 0, stream>>>(aB, bB, gemmP);
    corr_kernel<<<100, 256, 0, stream>>>(aB, bB, labels, corrP);
    reduce_kernel<<<1, 256, 0, stream>>>(gemmP, corrP, out);
}

// Round 9
// 118.637 us; speedup vs baseline: 1.2706x; 1.2249x over previous
//
#include <hip/hip_runtime.h>

typedef unsigned char u8;
typedef unsigned short u16;
typedef float f32x4 __attribute__((ext_vector_type(4)));
typedef int i32x4 __attribute__((ext_vector_type(4)));
typedef int i32x8 __attribute__((ext_vector_type(8)));

#define NROWS 16384
#define DIM 128

// exp(-2*sim) = exp2(sim * -2*log2(e)); scale folded into normalized B rows.
#define NEG2LOG2E -2.8853900817779268f
#define SCALE ((float)(1.0 / (16384.0 * 16383.0)))

// E8M0 scale byte 127 = 2^0 = 1.0, replicated.
#define SCALE1 0x7F7F7F7F

// Two rows per wave (half-wave per row): float4 loads, half-wave shuffle
// reduction, paired cvt_pk_fp8 -> one dword store per lane (fully coalesced).
// B rows pre-scaled by -2*log2(e) so GEMM output feeds exp2 directly.
__global__ __launch_bounds__(256) void norm_kernel(
    const float* __restrict__ a, const float* __restrict__ b,
    u8* __restrict__ aO, u8* __restrict__ bO)
{
    int tid  = threadIdx.x;
    int lane = tid & 63;
    int w    = tid >> 6;
    int half = lane >> 5;
    int l32  = lane & 31;
    long row = (long)blockIdx.x * 8 + w * 2 + half;

    const float4 va = ((const float4*)(a + row * DIM))[l32];
    float sa = va.x * va.x + va.y * va.y + va.z * va.z + va.w * va.w;
    #pragma unroll
    for (int off = 16; off; off >>= 1) sa += __shfl_xor(sa, off, 64);
    float inva = 1.0f / fmaxf(sqrtf(sa), 1e-12f);
    int pa = __builtin_amdgcn_cvt_pk_fp8_f32(va.x * inva, va.y * inva, 0, false);
    pa = __builtin_amdgcn_cvt_pk_fp8_f32(va.z * inva, va.w * inva, pa, true);
    ((int*)(aO + row * DIM))[l32] = pa;

    const float4 vb = ((const float4*)(b + row * DIM))[l32];
    float sb = vb.x * vb.x + vb.y * vb.y + vb.z * vb.z + vb.w * vb.w;
    #pragma unroll
    for (int off = 16; off; off >>= 1) sb += __shfl_xor(sb, off, 64);
    float invb = NEG2LOG2E / fmaxf(sqrtf(sb), 1e-12f);
    int pb = __builtin_amdgcn_cvt_pk_fp8_f32(vb.x * invb, vb.y * invb, 0, false);
    pb = __builtin_amdgcn_cvt_pk_fp8_f32(vb.z * invb, vb.w * invb, pb, true);
    ((int*)(bO + row * DIM))[l32] = pb;
}

// Each block: 128 rows x 512 cols = 4 column-tiles of 128x128.
// A tile (16 KB) staged once, A-operands register-resident (32 VGPRs).
// B double-buffered (2 x 16 KB): [issue DMA B_{t+1}] -> compute t -> barrier.
// MX-scaled fp8 MFMA 16x16x128 (scale=1.0): one instr per (mi,ni) covers
// K=128 at 2x rate. Operand = 32 B/lane = two swizzled b128 granules.
// Label mask applied in the epilogue (cmp+cndmask, ~+7 us VALU device-wide —
// measured cheaper than any separate same-label correction pass: R8's corr
// kernel cost ~39 us of pure latency).
__global__ __launch_bounds__(256, 3) void gemm_kernel(
    const u8* __restrict__ A, const u8* __restrict__ B,
    const int* __restrict__ labels, float* __restrict__ partials)
{
    __shared__ u8 sA[16384];
    __shared__ u8 sB[2][16384];

    int tid  = threadIdx.x;
    int lane = tid & 63;
    int w    = tid >> 6;
    int wr   = w >> 1;
    int wc   = w & 1;
    int mrow = lane & 15;
    int q    = lane >> 4;

    int rowBase = blockIdx.y * 128;      // grid (32,128): x = column group
    int colBase = blockIdx.x * 512;

    // Staging pattern: LDS granule g of row m holds global granule g^(m&7).
    int m0 = tid >> 3;
    int p0 = tid & 7;
    int srcOff = m0 * 128 + ((p0 ^ (m0 & 7)) << 4);
    int ldsOff = (tid - lane) * 16;      // wave-uniform base

    const u8* gA = A + (size_t)rowBase * DIM + srcOff;
    const u8* gB = B + (size_t)colBase * DIM + srcOff;

    {
        const u8* gpA = gA;
        const u8* gpB = gB;
        u8* lpA = &sA[ldsOff];
        u8* lpB = &sB[0][ldsOff];
        #pragma unroll
        for (int it = 0; it < 4; it++) {
            __builtin_amdgcn_global_load_lds(
                (const __attribute__((address_space(1))) void*)gpA,
                (__attribute__((address_space(3))) void*)lpA, 16, 0, 0);
            __builtin_amdgcn_global_load_lds(
                (const __attribute__((address_space(1))) void*)gpB,
                (__attribute__((address_space(3))) void*)lpB, 16, 0, 0);
            gpA += 4096; gpB += 4096; lpA += 4096; lpB += 4096;
        }
    }

    // Row labels (fixed for the whole block) — loads overlap the DMA.
    int iBase = rowBase + wr * 64 + q * 4;
    int li[16];
    #pragma unroll
    for (int mi = 0; mi < 4; mi++)
        #pragma unroll
        for (int r = 0; r < 4; r++)
            li[mi * 4 + r] = labels[iBase + mi * 16 + r];

    // Fragment LDS byte offsets: low granule (2q)^(row&7); high = ^16.
    int aOff[4], bOff[4];
    #pragma unroll
    for (int mi = 0; mi < 4; mi++) {
        int m = wr * 64 + mi * 16 + mrow;
        aOff[mi] = m * 128 + (((q << 1) ^ (m & 7)) << 4);
        int n = wc * 64 + mi * 16 + mrow;
        bOff[mi] = n * 128 + (((q << 1) ^ (n & 7)) << 4);
    }

    __syncthreads();   // A + B0 resident

    // A operands register-resident for all 4 tiles (32 VGPRs).
    i32x8 a8[4];
    #pragma unroll
    for (int mi = 0; mi < 4; mi++) {
        *((i32x4*)&a8[mi])     = *(const i32x4*)(sA + aOff[mi]);
        *((i32x4*)&a8[mi] + 1) = *(const i32x4*)(sA + (aOff[mi] ^ 16));
    }

    float s = 0.0f;

    #pragma unroll
    for (int jt = 0; jt < 4; jt++) {
        if (jt < 3) {
            const u8* gp = gB + (jt + 1) * (128 * DIM);
            u8* lp = &sB[(jt + 1) & 1][ldsOff];
            #pragma unroll
            for (int it = 0; it < 4; it++) {
                __builtin_amdgcn_global_load_lds(
                    (const __attribute__((address_space(1))) void*)gp,
                    (__attribute__((address_space(3))) void*)lp, 16, 0, 0);
                gp += 4096; lp += 4096;
            }
        }

        // Column labels for this tile (L1-hot; latency hidden under MFMA).
        int jBase = colBase + jt * 128 + wc * 64 + mrow;
        int lj[4];
        #pragma unroll
        for (int ni = 0; ni < 4; ni++)
            lj[ni] = labels[jBase + ni * 16];

        const u8* sb = sB[jt & 1];
        i32x8 b8[4];
        #pragma unroll
        for (int ni = 0; ni < 4; ni++) {
            *((i32x4*)&b8[ni])     = *(const i32x4*)(sb + bOff[ni]);
            *((i32x4*)&b8[ni] + 1) = *(const i32x4*)(sb + (bOff[ni] ^ 16));
        }

        f32x4 acc[4][4];
        #pragma unroll
        for (int mi = 0; mi < 4; mi++)
            #pragma unroll
            for (int ni = 0; ni < 4; ni++)
                acc[mi][ni] = (f32x4){0.f, 0.f, 0.f, 0.f};

        #pragma unroll
        for (int mi = 0; mi < 4; mi++)
            #pragma unroll
            for (int ni = 0; ni < 4; ni++)
                acc[mi][ni] = __builtin_amdgcn_mfma_scale_f32_16x16x128_f8f6f4(
                    a8[mi], b8[ni], acc[mi][ni], 0, 0, 0, SCALE1, 0, SCALE1);

        // Epilogue: exp2 + label mask + local sum.
        float s0 = 0.0f, s1 = 0.0f;
        #pragma unroll
        for (int mi = 0; mi < 4; mi++)
            #pragma unroll
            for (int ni = 0; ni < 4; ni++)
                #pragma unroll
                for (int r = 0; r < 4; r++) {
                    float e = __builtin_amdgcn_exp2f(acc[mi][ni][r]);
                    float m = (li[mi * 4 + r] != lj[ni]) ? e : 0.0f;
                    if (r & 1) s1 += m; else s0 += m;
                }
        s += s0 + s1;

        __syncthreads();
    }

    #pragma unroll
    for (int off = 32; off; off >>= 1) s += __shfl_xor(s, off, 64);

    float* red = (float*)sA;
    if (lane == 0) red[w] = s;
    __syncthreads();
    if (tid == 0) {
        float t = (red[0] + red[1]) + (red[2] + red[3]);
        partials[blockIdx.y * 32 + blockIdx.x] = t * SCALE;
    }
}

__global__ __launch_bounds__(256) void reduce_kernel(
    const float* __restrict__ gP, float* __restrict__ out)
{
    int tid = threadIdx.x;
    const float4* p4 = (const float4*)gP;
    float s = 0.0f;
    #pragma unroll 4
    for (int i = tid; i < 1024; i += 256) {
        float4 v = p4[i];
        s += (v.x + v.y) + (v.z + v.w);
    }
    #pragma unroll
    for (int off = 32; off; off >>= 1) s += __shfl_xor(s, off, 64);
    __shared__ float red[4];
    if ((tid & 63) == 0) red[tid >> 6] = s;
    __syncthreads();
    if (tid == 0) out[0] = (red[0] + red[1]) + (red[2] + red[3]);
}

extern "C" void kernel_launch(void* const* d_in, const int* in_sizes, int n_in,
                              void* d_out, int out_size, void* d_ws, size_t ws_size,
                              hipStream_t stream) {
    const float* self_p = (const float*)d_in[0];
    const float* pos_p  = (const float*)d_in[1];
    const int*   labels = (const int*)d_in[2];
    float* out = (float*)d_out;

    u8* aB = (u8*)d_ws;                         // 2 MB fp8 normalized self
    u8* bB = aB + (size_t)NROWS * DIM;          // 2 MB fp8 normalized pos (pre-scaled)
    float* gemmP = (float*)(bB + (size_t)NROWS * DIM);     // 16 KB

    norm_kernel<<<NROWS / 8, 256, 0, stream>>>(self_p, pos_p, aB, bB);
    gemm_kernel<<<dim3(32, 128), 256, 0, stream>>>(aB, bB, labels, gemmP);
    reduce_kernel<<<1, 256, 0, stream>>>(gemmP, out);
}